// Round 3
// baseline (263.242 us; speedup 1.0000x reference)
//
#include <hip/hip_runtime.h>

#define B_    2048
#define K_    32
#define D_    768
#define DICT_ 24576
#define C_    64

#define BD_   16     // dict columns per transpose block (= one 64B line)
#define TS_   772    // LDS row stride in floats (768 + 4 pad: 2-way banks, 16B aligned)

// K0: transpose up_decoder_w [D][DICT] -> T [DICT][D].
// Each block owns 16 dict columns x all 768 d: its output is 16 complete
// T-rows = one CONTIGUOUS 48 KB span. (Round-2 lesson: 256B-granular strided
// writes pinned the transpose at 2.5 TB/s regardless of read-side tiling.)
// Reads: 64B chunks (4 lanes x float4) at row stride; each HBM line consumed
// entirely by exactly one block -> no over-fetch.
__global__ __launch_bounds__(256) void transpose_kernel(const float* __restrict__ A,
                                                        float* __restrict__ T) {
    __shared__ float lds[BD_ * TS_];
    int x0  = blockIdx.x * BD_;
    int sub = threadIdx.x & 3;          // which float4 of the 16-col chunk
    int dr  = threadIdx.x >> 2;         // 0..63: d-row within a pass

    float4 v[12];
    #pragma unroll
    for (int p = 0; p < 12; ++p) {      // 12 passes x 64 rows = 768 d
        int d = dr + 64 * p;
        v[p] = *(const float4*)(A + (size_t)d * DICT_ + x0 + 4 * sub);
    }
    #pragma unroll
    for (int p = 0; p < 12; ++p) {
        int d = dr + 64 * p;
        lds[(4 * sub + 0) * TS_ + d] = v[p].x;   // banks: 2-way aliased (free)
        lds[(4 * sub + 1) * TS_ + d] = v[p].y;
        lds[(4 * sub + 2) * TS_ + d] = v[p].z;
        lds[(4 * sub + 3) * TS_ + d] = v[p].w;
    }
    __syncthreads();

    int wave = threadIdx.x >> 6;
    int lane = threadIdx.x & 63;
    float4 w[12];
    #pragma unroll
    for (int rr = 0; rr < 4; ++rr) {
        int r = 4 * wave + rr;          // T-row-local (dict-local col)
        #pragma unroll
        for (int i = 0; i < 3; ++i)
            w[rr * 3 + i] = *(const float4*)&lds[r * TS_ + 4 * (lane + 64 * i)];
    }
    #pragma unroll
    for (int rr = 0; rr < 4; ++rr) {
        int r = 4 * wave + rr;
        #pragma unroll
        for (int i = 0; i < 3; ++i)
            *(float4*)(T + (size_t)(x0 + r) * D_ + 4 * (lane + 64 * i)) = w[rr * 3 + i];
    }
}

// K1: bdc[r] = dot(up_encoder_w[r,:], b_dec)   (one wave per row, float4)
__global__ void bdc_kernel(const float* __restrict__ up_enc,
                           const float* __restrict__ b_dec,
                           float* __restrict__ bdc) {
    int wave = threadIdx.x >> 6;
    int lane = threadIdx.x & 63;
    int row  = blockIdx.x * 4 + wave;
    const float4* rp = (const float4*)(up_enc + (size_t)row * D_);
    const float4* bp = (const float4*)b_dec;
    float acc = 0.f;
    #pragma unroll
    for (int i = 0; i < 3; ++i) {
        float4 a = rp[lane + 64 * i];
        float4 b = bp[lane + 64 * i];
        acc += a.x * b.x + a.y * b.y + a.z * b.z + a.w * b.w;
    }
    #pragma unroll
    for (int off = 32; off; off >>= 1) acc += __shfl_xor(acc, off);
    if (lane == 0) bdc[row] = acc;
}

// K2: one wave per (b,i). Cheap unrolled readlane match-scan (matches ~0.075/item);
// rare pair-dots read T rows coalesced (float4) instead of up_dec columns
// (scattered columns cost 16x line over-fetch: 248 MB HBM, measured round 1).
__global__ void main_kernel(const float* __restrict__ up_vals,
                            const float* __restrict__ up_dec,
                            const float* __restrict__ down_enc,
                            const float* __restrict__ up_enc,
                            const float* __restrict__ b_dec,
                            const int*   __restrict__ up_idx,
                            const int*   __restrict__ down_idx,
                            const int*   __restrict__ conn,
                            const float* __restrict__ T,    // may be null
                            const float* __restrict__ bdc,  // may be null
                            float* __restrict__ out) {
    int wave = threadIdx.x >> 6;
    int lane = threadIdx.x & 63;
    int item = blockIdx.x * 4 + wave;      // item = b*32 + i
    int b    = item >> 5;

    int di = down_idx[item];
    int allowed = conn[(size_t)di * C_ + lane];   // lane c holds slot c (C_==64)
    bool valid = allowed >= 0;
    int   myup  = up_idx[b * K_ + (lane & 31)];
    float myval = up_vals[b * K_ + (lane & 31)];

    // Per-lane bitmask of which j's this slot matches. Compile-time j makes
    // __builtin_amdgcn_readlane an SGPR broadcast: ~3 VALU ops per j.
    unsigned jm = 0u;
    #pragma unroll
    for (int j = 0; j < K_; ++j) {
        int tgt = __builtin_amdgcn_readlane(myup, j);
        jm |= (valid && (allowed == tgt)) ? (1u << j) : 0u;
    }

    float acc = 0.f;
    if (__ballot(jm != 0u)) {              // wave-uniform; ~7% of items
        const float* drow = down_enc + (size_t)di * D_;
        #pragma unroll 1
        for (int j = 0; j < K_; ++j) {
            unsigned long long m = __ballot((jm >> j) & 1u);
            if (m != 0) {                  // wave-uniform branch
                float w   = (float)__popcll(m) * __shfl(myval, j);
                int   tgt = __shfl(myup, j);
                float partial = 0.f;
                if (T) {
                    const float4* cp = (const float4*)(T + (size_t)tgt * D_);
                    const float4* dp = (const float4*)drow;
                    #pragma unroll
                    for (int ii = 0; ii < 3; ++ii) {
                        float4 c = cp[lane + 64 * ii];
                        float4 d = dp[lane + 64 * ii];
                        partial += c.x * d.x + c.y * d.y + c.z * d.z + c.w * d.w;
                    }
                } else {
                    const float* colp = up_dec + tgt;
                    #pragma unroll
                    for (int ii = 0; ii < 12; ++ii) {
                        int d = lane + 64 * ii;
                        partial += drow[d] * colp[(size_t)d * DICT_];
                    }
                }
                acc += w * partial;
            }
        }
    }

    if (!bdc) {  // inline bias fallback (no workspace)
        int ui = up_idx[item];
        const float4* rp = (const float4*)(up_enc + (size_t)ui * D_);
        const float4* bp = (const float4*)b_dec;
        #pragma unroll
        for (int ii = 0; ii < 3; ++ii) {
            float4 a  = rp[lane + 64 * ii];
            float4 bb = bp[lane + 64 * ii];
            acc += a.x * bb.x + a.y * bb.y + a.z * bb.z + a.w * bb.w;
        }
    }

    #pragma unroll
    for (int off = 32; off; off >>= 1) acc += __shfl_xor(acc, off);
    if (lane == 0) {
        float bias = bdc ? bdc[up_idx[item]] : 0.f;
        out[item] = acc + bias;
    }
}

extern "C" void kernel_launch(void* const* d_in, const int* in_sizes, int n_in,
                              void* d_out, int out_size, void* d_ws, size_t ws_size,
                              hipStream_t stream) {
    (void)in_sizes; (void)n_in; (void)out_size;
    const float* up_vals  = (const float*)d_in[0];
    const float* up_dec   = (const float*)d_in[1];
    const float* down_enc = (const float*)d_in[2];
    const float* up_enc   = (const float*)d_in[3];
    const float* b_dec    = (const float*)d_in[4];
    const int*   up_idx   = (const int*)d_in[5];
    const int*   down_idx = (const int*)d_in[6];
    const int*   conn     = (const int*)d_in[7];
    float* out = (float*)d_out;

    size_t bdc_bytes = (size_t)DICT_ * sizeof(float);
    size_t T_bytes   = (size_t)DICT_ * D_ * sizeof(float);
    float* bdc = (ws_size >= bdc_bytes) ? (float*)d_ws : nullptr;
    float* T   = (ws_size >= bdc_bytes + T_bytes) ? (float*)d_ws + DICT_ : nullptr;

    if (T) {
        transpose_kernel<<<DICT_ / BD_, 256, 0, stream>>>(up_dec, T);
    }
    if (bdc) {
        bdc_kernel<<<DICT_ / 4, 256, 0, stream>>>(up_enc, b_dec, bdc);
    }
    main_kernel<<<(B_ * K_) / 4, 256, 0, stream>>>(up_vals, up_dec, down_enc, up_enc,
                                                   b_dec, up_idx, down_idx, conn,
                                                   T, bdc, out);
}